// Round 2
// baseline (568.493 us; speedup 1.0000x reference)
//
#include <hip/hip_runtime.h>
#include <stdint.h>

typedef __attribute__((ext_vector_type(8))) short short8;
typedef __attribute__((ext_vector_type(4))) float f32x4;

#define DEV static __device__ __forceinline__

DEV float b2f(unsigned short u) {
  unsigned x = ((unsigned)u) << 16;
  return __builtin_bit_cast(float, x);
}
DEV unsigned short f2b(float f) {
  unsigned x = __builtin_bit_cast(unsigned, f);
  return (unsigned short)((x + 0x7fffu + ((x >> 16) & 1u)) >> 16);
}
DEV void gload16(const unsigned short* g, unsigned short* l) {
  __builtin_amdgcn_global_load_lds((const __attribute__((address_space(1))) void*)g,
                                   (__attribute__((address_space(3))) void*)l, 16, 0, 0);
}
#define MFMA(a, b, c) __builtin_amdgcn_mfma_f32_16x16x32_bf16(a, b, c, 0, 0, 0)

// ---------------- fp32 -> bf16 convert ----------------
__global__ void k_f2b(const float* __restrict__ in, unsigned short* __restrict__ out, long n) {
  long i = ((long)blockIdx.x * blockDim.x + threadIdx.x) * 4;
  long stride = (long)gridDim.x * blockDim.x * 4;
  for (; i < n; i += stride) {
    float4 f = *(const float4*)(in + i);
    ushort4 o;
    o.x = f2b(f.x); o.y = f2b(f.y); o.z = f2b(f.z); o.w = f2b(f.w);
    *(ushort4*)(out + i) = o;
  }
}

// ---------------- 256x256-tile 8-wave counted-vmcnt bf16 GEMM (A[M][K], B[N][K]) ----------------
// Stage units per K-tile (BK=64): slot0 = A m-half0 (rows {0-63,128-191}), slot1 = B n-half0
// (rows {wn*64+0..31}), slot2 = A m-half1, slot3 = B n-half1. Phase p computes quadrant
// (mh=p>>1, nh=p&1); slot deaths: s0 after p1, s1 after p2, s2/s3 after p3. Stage lead = 6 units
// (phase g stages unit g+6) -> overwrites only dead slots, vmcnt(6) at ends of phases 0,2.
// LDS XOR swizzle kb^=(pos&7) via pre-swizzled global source (linear global_load_lds dest).
template <int MODE>
__global__ __launch_bounds__(512, 2) void k_gemm(
    const unsigned short* __restrict__ A, const unsigned short* __restrict__ B0,
    const unsigned short* __restrict__ B1,
    unsigned short* __restrict__ o_q, unsigned short* __restrict__ o_k,
    unsigned short* __restrict__ o_v, unsigned short* __restrict__ o_g,
    float* __restrict__ o_f) {
  const int K = 2048, NT = 32;  // K fixed for both GEMMs
  __shared__ unsigned short sm[65536];  // 128 KiB: 2 bufs x 4 units x 8192 shorts
  int tid = threadIdx.x, w = tid >> 6, lane = tid & 63;
  int wm = w >> 2, wn = w & 3;
  int l15 = lane & 15, l4 = lane >> 4;
  int cpx = gridDim.x >> 3;
  int bid = blockIdx.x;
  int swz = (bid & 7) * cpx + (bid >> 3);
  int tm = swz & 31, tn = swz >> 5;
  int brow = tm << 8, bcol = tn << 8;
  const unsigned short* Ab = A + (size_t)brow * K;
  const unsigned short* Bb = (MODE == 1 || bcol < 6144) ? (B0 + (size_t)bcol * K)
                                                        : (B1 + (size_t)(bcol - 6144) * K);
  f32x4 acc[8][4];
#pragma unroll
  for (int m = 0; m < 8; m++)
#pragma unroll
    for (int n = 0; n < 4; n++) acc[m][n] = (f32x4)0.f;

  auto stage = [&](int U) {
    if (U >= 4 * NT) return;
    int tt = U >> 2, s = U & 3;
    unsigned short* lb = sm + (tt & 1) * 32768 + s * 8192;
    int kt = tt << 6;
#pragma unroll
    for (int i = 0; i < 2; ++i) {
      int c = i * 512 + tid;
      int pos = c >> 3, pb = c & 7;
      int gcol = kt + ((pb ^ (pos & 7)) << 3);
      const unsigned short* src;
      if (s == 0) src = Ab + (size_t)((pos >> 6) * 128 + (pos & 63)) * K + gcol;
      else if (s == 2) src = Ab + (size_t)((pos >> 6) * 128 + 64 + (pos & 63)) * K + gcol;
      else if (s == 1) src = Bb + (size_t)((pos >> 5) * 64 + (pos & 31)) * K + gcol;
      else src = Bb + (size_t)((pos >> 5) * 64 + 32 + (pos & 31)) * K + gcol;
      gload16(src, lb + c * 8);
    }
  };

  // prologue: 6 units in flight, wait for first 2 (tile-0 slots 0,1)
  for (int U = 0; U < 6; ++U) stage(U);
  asm volatile("s_waitcnt vmcnt(8)" ::: "memory");
  __builtin_amdgcn_s_barrier();
  asm volatile("" ::: "memory");

  for (int T = 0; T < NT; ++T) {
    const unsigned short* bufb = sm + (T & 1) * 32768;
#pragma unroll
    for (int p = 0; p < 4; ++p) {
      const int mh = p >> 1, nh = p & 1;
      const unsigned short* Abase = bufb + (mh ? 2 : 0) * 8192;
      const unsigned short* Bbase = bufb + (nh ? 3 : 1) * 8192;
      short8 af[4][2], bfr[2][2];
#pragma unroll
      for (int mi = 0; mi < 4; ++mi) {
        int pos = wm * 64 + mi * 16 + l15;
        int px = pos * 64, hh = pos & 7;
#pragma unroll
        for (int ks = 0; ks < 2; ++ks)
          af[mi][ks] = *(const short8*)(Abase + px + (((ks * 4 + l4) ^ hh) << 3));
      }
#pragma unroll
      for (int ni = 0; ni < 2; ++ni) {
        int pos = wn * 32 + ni * 16 + l15;
        int px = pos * 64, hh = pos & 7;
#pragma unroll
        for (int ks = 0; ks < 2; ++ks)
          bfr[ni][ks] = *(const short8*)(Bbase + px + (((ks * 4 + l4) ^ hh) << 3));
      }
      stage(4 * T + p + 6);
      asm volatile("" ::: "memory");
      __builtin_amdgcn_s_barrier();
      asm volatile("" ::: "memory");
      __builtin_amdgcn_s_setprio(1);
#pragma unroll
      for (int mi = 0; mi < 4; ++mi)
#pragma unroll
        for (int ni = 0; ni < 2; ++ni)
#pragma unroll
          for (int ks = 0; ks < 2; ++ks)
            acc[mh * 4 + mi][nh * 2 + ni] =
                MFMA(af[mi][ks], bfr[ni][ks], acc[mh * 4 + mi][nh * 2 + ni]);
      __builtin_amdgcn_s_setprio(0);
      if (p == 0 || p == 2) asm volatile("s_waitcnt vmcnt(6)" ::: "memory");
      asm volatile("" ::: "memory");
      __builtin_amdgcn_s_barrier();
      asm volatile("" ::: "memory");
    }
  }

#pragma unroll
  for (int mi = 0; mi < 8; ++mi)
#pragma unroll
    for (int r = 0; r < 4; ++r) {
      int row = brow + wm * 128 + mi * 16 + l4 * 4 + r;
#pragma unroll
      for (int ni = 0; ni < 4; ++ni) {
        int col = bcol + wn * 64 + ni * 16 + l15;
        float v = acc[mi][ni][r];
        if (MODE == 0) {
          if (col < 6144) {
            float sv = v / (1.f + __expf(-v));  // silu
            int h = col / 384, dd = col - h * 384;
            int b = row >> 12, t = row & 4095;
            size_t base = ((size_t)(b * 16 + h) * 4096 + t) * 128;
            if (dd < 128) o_q[base + dd] = f2b(sv);
            else if (dd < 256) o_k[base + dd - 128] = f2b(sv);
            else o_v[base + dd - 256] = f2b(sv);
          } else {
            float gv = 1.f / (1.f + __expf(-v));  // sigmoid
            o_g[(size_t)row * 2048 + (col - 6144)] = f2b(gv);
          }
        } else {
          o_f[(size_t)row * 2048 + col] = v;
        }
      }
    }
}

// ---------------- per-block KV contribution: kvT[e][d] = sum_t V[t][e] * K[t][d]*kd[t] ----------------
__global__ __launch_bounds__(256) void k_kvblk(const unsigned short* __restrict__ kk,
                                               const unsigned short* __restrict__ vv,
                                               const float* __restrict__ slope,
                                               unsigned short* __restrict__ kvT) {
  int gid = blockIdx.x;  // 512 = bh*16 + blk
  int bh = gid >> 4, blk = gid & 15;
  float s = slope[bh & 15];
  __shared__ unsigned short kT[128][72];
  __shared__ unsigned short vT[128][72];
  int tid = threadIdx.x, w = tid >> 6, lane = tid & 63;
  int wrow = (w >> 1) * 64, wcol = (w & 1) * 64;
  f32x4 acc[4][4];
#pragma unroll
  for (int m = 0; m < 4; m++)
#pragma unroll
    for (int n = 0; n < 4; n++) acc[m][n] = (f32x4)0.f;
  const unsigned short* kb = kk + ((size_t)bh * 4096 + blk * 256) * 128;
  const unsigned short* vb = vv + ((size_t)bh * 4096 + blk * 256) * 128;
  int tt = tid & 63, c0 = (tid >> 6) * 32;
  for (int tc = 0; tc < 4; ++tc) {
    __syncthreads();
    int tg = tc * 64 + tt;
    float kd = __expf(-s * (float)(255 - tg));
#pragma unroll
    for (int g = 0; g < 4; ++g) {
      int c = c0 + g * 8;
      short8 k8 = *(const short8*)(kb + (size_t)tg * 128 + c);
      short8 v8 = *(const short8*)(vb + (size_t)tg * 128 + c);
#pragma unroll
      for (int j = 0; j < 8; ++j) {
        kT[c + j][tt] = f2b(b2f((unsigned short)k8[j]) * kd);
        vT[c + j][tt] = (unsigned short)v8[j];
      }
    }
    __syncthreads();
#pragma unroll
    for (int kx = 0; kx < 64; kx += 32) {
      int ko = kx + (lane >> 4) * 8;
      short8 af[4], bfr[4];
#pragma unroll
      for (int m = 0; m < 4; m++) af[m] = *(const short8*)&vT[wrow + m * 16 + (lane & 15)][ko];
#pragma unroll
      for (int n = 0; n < 4; n++) bfr[n] = *(const short8*)&kT[wcol + n * 16 + (lane & 15)][ko];
#pragma unroll
      for (int m = 0; m < 4; m++)
#pragma unroll
        for (int n = 0; n < 4; n++) acc[m][n] = MFMA(af[m], bfr[n], acc[m][n]);
    }
  }
  unsigned short* op = kvT + (size_t)gid * 16384;
#pragma unroll
  for (int m = 0; m < 4; m++)
#pragma unroll
    for (int r = 0; r < 4; r++) {
      int e = wrow + m * 16 + (lane >> 4) * 4 + r;
#pragma unroll
      for (int n = 0; n < 4; n++) {
        int d = wcol + n * 16 + (lane & 15);
        op[e * 128 + d] = f2b(acc[m][n][r]);
      }
    }
}

// ---------------- decay prefix scan over blocks (in place: kvT[i] := state before block i) ----------------
__global__ void k_scan(unsigned short* kvT, const float* __restrict__ slope) {
  int gid = blockIdx.x;  // 2048
  int bh = gid >> 6;
  int eo = (gid & 63) * 256 + threadIdx.x;  // 0..16383
  float s = slope[bh & 15];
  float bd = __expf(-s * 256.f);
  float st = 0.f;
  size_t base = (size_t)bh * 16 * 16384 + eo;
#pragma unroll
  for (int i = 0; i < 16; ++i) {
    unsigned short c = kvT[base + (size_t)i * 16384];
    kvT[base + (size_t)i * 16384] = f2b(st);
    st = bd * st + b2f(c);
  }
}

// ---------------- per-block attention output ----------------
__global__ __launch_bounds__(256) void k_attn(const unsigned short* __restrict__ q,
                                              const unsigned short* __restrict__ kk,
                                              const unsigned short* __restrict__ vv,
                                              const unsigned short* __restrict__ kvT,
                                              const float* __restrict__ slope,
                                              unsigned short* __restrict__ attn) {
  int gid = blockIdx.x;  // 1024 = (bh*16 + blk)*2 + hf
  int hf = gid & 1, blk = (gid >> 1) & 15, bh = gid >> 5;
  float s = slope[bh & 15];
  __shared__ unsigned short k_sh[64][136];
  __shared__ unsigned short vT_sh[128][72];
  __shared__ unsigned short s_sh[4][32][72];
  int tid = threadIdx.x, w = tid >> 6, lane = tid & 63;
  int mm0 = hf * 128 + w * 32;  // wave's first within-block row
  const unsigned short* qb = q + ((size_t)bh * 4096 + blk * 256) * 128;
  const unsigned short* kvb = kvT + (size_t)(bh * 16 + blk) * 16384;
  f32x4 acc[2][8];
#pragma unroll
  for (int m = 0; m < 2; m++)
#pragma unroll
    for (int n = 0; n < 8; n++) acc[m][n] = (f32x4)0.f;
  // inter-block: (q) @ KV_pre   (row-scale by q_decay afterwards)
#pragma unroll
  for (int kx = 0; kx < 128; kx += 32) {
    int ko = kx + (lane >> 4) * 8;
    short8 af[2], bfr[8];
#pragma unroll
    for (int mi = 0; mi < 2; mi++)
      af[mi] = *(const short8*)(qb + (size_t)(mm0 + mi * 16 + (lane & 15)) * 128 + ko);
#pragma unroll
    for (int ni = 0; ni < 8; ni++)
      bfr[ni] = *(const short8*)(kvb + (size_t)(ni * 16 + (lane & 15)) * 128 + ko);
#pragma unroll
    for (int mi = 0; mi < 2; mi++)
#pragma unroll
      for (int ni = 0; ni < 8; ni++) acc[mi][ni] = MFMA(af[mi], bfr[ni], acc[mi][ni]);
  }
#pragma unroll
  for (int mi = 0; mi < 2; mi++)
#pragma unroll
    for (int r = 0; r < 4; r++) {
      float qd = __expf(-s * (float)(mm0 + mi * 16 + (lane >> 4) * 4 + r + 1));
#pragma unroll
      for (int ni = 0; ni < 8; ni++) acc[mi][ni][r] *= qd;
    }
  // intra-block: masked quadratic attention, 64-wide t-chunks
  int nchunk = 2 * (hf + 1);
  for (int tc = 0; tc < nchunk; ++tc) {
    __syncthreads();
    {  // stage K chunk rows [t][d]
      int t2 = tid >> 2, c = (tid & 3) * 32;
      const unsigned short* kp = kk + ((size_t)bh * 4096 + blk * 256 + tc * 64 + t2) * 128 + c;
#pragma unroll
      for (int g = 0; g < 4; ++g) *(short8*)&k_sh[t2][c + g * 8] = *(const short8*)(kp + g * 8);
    }
    {  // stage V^T chunk [e][t]
      int t2 = tid & 63, e0 = (tid >> 6) * 32;
      const unsigned short* vp = vv + ((size_t)bh * 4096 + blk * 256 + tc * 64 + t2) * 128 + e0;
#pragma unroll
      for (int g = 0; g < 4; ++g) {
        short8 v8 = *(const short8*)(vp + g * 8);
#pragma unroll
        for (int j = 0; j < 8; ++j) vT_sh[e0 + g * 8 + j][t2] = (unsigned short)v8[j];
      }
    }
    __syncthreads();
    if (tc * 64 <= mm0 + 31) {
      f32x4 sa[2][4];
#pragma unroll
      for (int m = 0; m < 2; m++)
#pragma unroll
        for (int n = 0; n < 4; n++) sa[m][n] = (f32x4)0.f;
#pragma unroll
      for (int kx = 0; kx < 128; kx += 32) {
        int ko = kx + (lane >> 4) * 8;
        short8 af[2], bfr[4];
#pragma unroll
        for (int mi = 0; mi < 2; mi++)
          af[mi] = *(const short8*)(qb + (size_t)(mm0 + mi * 16 + (lane & 15)) * 128 + ko);
#pragma unroll
        for (int ni = 0; ni < 4; ni++) bfr[ni] = *(const short8*)&k_sh[ni * 16 + (lane & 15)][ko];
#pragma unroll
        for (int mi = 0; mi < 2; mi++)
#pragma unroll
          for (int ni = 0; ni < 4; ni++) sa[mi][ni] = MFMA(af[mi], bfr[ni], sa[mi][ni]);
      }
      // mask * decay, to bf16, into per-wave S tile
#pragma unroll
      for (int mi = 0; mi < 2; mi++)
#pragma unroll
        for (int ni = 0; ni < 4; ni++)
#pragma unroll
          for (int r = 0; r < 4; r++) {
            int mm = mm0 + mi * 16 + (lane >> 4) * 4 + r;
            int ttg = tc * 64 + ni * 16 + (lane & 15);
            int diff = mm - ttg;
            float val = (diff >= 0) ? sa[mi][ni][r] * __expf(-s * (float)diff) : 0.f;
            s_sh[w][mi * 16 + (lane >> 4) * 4 + r][ni * 16 + (lane & 15)] = f2b(val);
          }
      // O += S @ V
#pragma unroll
      for (int k2 = 0; k2 < 64; k2 += 32) {
        int ko2 = k2 + (lane >> 4) * 8;
        short8 a2[2];
#pragma unroll
        for (int mi = 0; mi < 2; mi++)
          a2[mi] = *(const short8*)&s_sh[w][mi * 16 + (lane & 15)][ko2];
#pragma unroll
        for (int ni = 0; ni < 8; ni++) {
          short8 b2 = *(const short8*)&vT_sh[ni * 16 + (lane & 15)][ko2];
#pragma unroll
          for (int mi = 0; mi < 2; mi++) acc[mi][ni] = MFMA(a2[mi], b2, acc[mi][ni]);
        }
      }
    }
  }
  int b = bh >> 4, h = bh & 15;
#pragma unroll
  for (int mi = 0; mi < 2; mi++)
#pragma unroll
    for (int r = 0; r < 4; r++) {
      int mm = mm0 + mi * 16 + (lane >> 4) * 4 + r;
      size_t rowp = ((size_t)b * 4096 + blk * 256 + mm) * 2048 + h * 128;
#pragma unroll
      for (int ni = 0; ni < 8; ni++) attn[rowp + ni * 16 + (lane & 15)] = f2b(acc[mi][ni][r]);
    }
}

// ---------------- RMSNorm + gate ----------------
__global__ __launch_bounds__(256) void k_norm(const unsigned short* __restrict__ attn,
                                              const unsigned short* __restrict__ gate,
                                              const float* __restrict__ nw,
                                              unsigned short* __restrict__ y) {
  int row = blockIdx.x;  // 8192
  int tid = threadIdx.x, w = tid >> 6, lane = tid & 63;
  const unsigned short* ap = attn + (size_t)row * 2048 + tid * 8;
  const unsigned short* gp = gate + (size_t)row * 2048 + tid * 8;
  short8 a8 = *(const short8*)ap;
  float vals[8];
  float ss = 0.f;
#pragma unroll
  for (int j = 0; j < 8; ++j) {
    vals[j] = b2f((unsigned short)a8[j]);
    ss += vals[j] * vals[j];
  }
#pragma unroll
  for (int off = 32; off > 0; off >>= 1) ss += __shfl_down(ss, off, 64);
  __shared__ float red[4];
  if (lane == 0) red[w] = ss;
  __syncthreads();
  float tot = red[0] + red[1] + red[2] + red[3];
  float rms = rsqrtf(tot * (1.f / 2048.f) + 1.1920929e-07f);
  short8 g8 = *(const short8*)gp;
  short8 o;
#pragma unroll
  for (int j = 0; j < 8; ++j)
    o[j] = (short)f2b(vals[j] * rms * nw[tid * 8 + j] * b2f((unsigned short)g8[j]));
  *(short8*)(y + (size_t)row * 2048 + tid * 8) = o;
}

extern "C" void kernel_launch(void* const* d_in, const int* in_sizes, int n_in, void* d_out,
                              int out_size, void* d_ws, size_t ws_size, hipStream_t stream) {
  const float* x = (const float*)d_in[0];
  const float* slope = (const float*)d_in[1];
  const float* Wqkv = (const float*)d_in[2];
  const float* Wg = (const float*)d_in[3];
  const float* nw = (const float*)d_in[4];
  const float* Wo = (const float*)d_in[5];
  float* out = (float*)d_out;

  unsigned short* q = (unsigned short*)d_ws;               // 16,777,216 elems
  unsigned short* k = q + 16777216;                        // 16,777,216
  unsigned short* v = k + 16777216;                        // 16,777,216
  unsigned short* gate = v + 16777216;                     // 16,777,216
  unsigned short* xb = gate + 16777216;                    // 16,777,216
  unsigned short* wqkvb = xb + 16777216;                   // 12,582,912
  unsigned short* wgb = wqkvb + 12582912;                  // 4,194,304
  unsigned short* wob = wgb + 4194304;                     // 4,194,304
  unsigned short* kvT = wob + 4194304;                     // 8,388,608
  unsigned short* attn = wqkvb;  // alias: wqkvb+wgb dead after GEMM1 (exactly 16,777,216)
  unsigned short* y = xb;        // alias: xb dead after GEMM1

  k_f2b<<<2048, 256, 0, stream>>>(x, xb, 16777216L);
  k_f2b<<<2048, 256, 0, stream>>>(Wqkv, wqkvb, 12582912L);
  k_f2b<<<1024, 256, 0, stream>>>(Wg, wgb, 4194304L);
  k_f2b<<<1024, 256, 0, stream>>>(Wo, wob, 4194304L);

  k_gemm<0><<<1024, 512, 0, stream>>>(xb, wqkvb, wgb, q, k, v, gate, nullptr);
  k_kvblk<<<512, 256, 0, stream>>>(k, v, slope, kvT);
  k_scan<<<2048, 256, 0, stream>>>(kvT, slope);
  k_attn<<<1024, 256, 0, stream>>>(q, k, v, kvT, slope, attn);
  k_norm<<<8192, 256, 0, stream>>>(attn, gate, nw, y);
  k_gemm<1><<<256, 512, 0, stream>>>(y, wob, nullptr, nullptr, nullptr, nullptr, nullptr, out);
}

// Round 3
// 505.400 us; speedup vs baseline: 1.1248x; 1.1248x over previous
//
#include <hip/hip_runtime.h>
#include <stdint.h>

typedef __attribute__((ext_vector_type(8))) short short8;
typedef __attribute__((ext_vector_type(4))) float f32x4;

#define DEV static __device__ __forceinline__

DEV float b2f(unsigned short u) {
  unsigned x = ((unsigned)u) << 16;
  return __builtin_bit_cast(float, x);
}
DEV unsigned short f2b(float f) {
  unsigned x = __builtin_bit_cast(unsigned, f);
  return (unsigned short)((x + 0x7fffu + ((x >> 16) & 1u)) >> 16);
}
DEV void gload16(const unsigned short* g, unsigned short* l) {
  __builtin_amdgcn_global_load_lds((const __attribute__((address_space(1))) void*)g,
                                   (__attribute__((address_space(3))) void*)l, 16, 0, 0);
}
#define MFMA(a, b, c) __builtin_amdgcn_mfma_f32_16x16x32_bf16(a, b, c, 0, 0, 0)

// ---------------- fp32 -> bf16 convert ----------------
__global__ void k_f2b(const float* __restrict__ in, unsigned short* __restrict__ out, long n) {
  long i = ((long)blockIdx.x * blockDim.x + threadIdx.x) * 4;
  long stride = (long)gridDim.x * blockDim.x * 4;
  for (; i < n; i += stride) {
    float4 f = *(const float4*)(in + i);
    ushort4 o;
    o.x = f2b(f.x); o.y = f2b(f.y); o.z = f2b(f.z); o.w = f2b(f.w);
    *(ushort4*)(out + i) = o;
  }
}

// ---------------- 256x256-tile 8-wave 2-phase bf16 GEMM (A[M][K], B[N][K]) ----------------
// LDS slots per K-tile (BK=64): 0 = A rows 0..127, 1 = B rows 0..127, 2 = A rows 128..255,
// 3 = B rows 128..255. Phase 0: af<-slot0, bfr<-slot1/3 (held in regs), 32 MFMA (C rows 0..127).
// Phase 1: af<-slot2, 32 MFMA (C rows 128..255). Stage lead: at T.p0 stage (T+1){0,1,3}, at
// T.p1 stage (T+1){2}. Counted waits: vmcnt(6) end p0 (unit2(T) done), vmcnt(2) end p1
// (units 0,1,3 of T+1 done). LDS XOR swizzle (chunk ^ pos&7) via pre-swizzled global source.
// XCD chunking: tm = xcd*4 + (sub&3), tn = sub>>2 -> concurrent set ~4tm x 8tn per XCD.
template <int MODE>
__global__ __launch_bounds__(512, 2) void k_gemm(
    const unsigned short* __restrict__ A, const unsigned short* __restrict__ B0,
    const unsigned short* __restrict__ B1,
    unsigned short* __restrict__ o_q, unsigned short* __restrict__ o_k,
    unsigned short* __restrict__ o_v, unsigned short* __restrict__ o_g,
    float* __restrict__ o_f) {
  const int K = 2048, NT = 32;
  __shared__ unsigned short sm[65536];  // 128 KiB: 2 bufs x 4 slots x 8192 shorts
  int tid = threadIdx.x, w = tid >> 6, lane = tid & 63;
  int wm = w >> 2, wn = w & 3;
  int l15 = lane & 15, l4 = lane >> 4;
  int xcd = blockIdx.x & 7, sub = blockIdx.x >> 3;
  int tm = xcd * 4 + (sub & 3), tn = sub >> 2;
  int brow = tm << 8, bcol = tn << 8;
  const unsigned short* Ab = A + (size_t)brow * K;
  const unsigned short* Bb = (MODE == 1 || bcol < 6144) ? (B0 + (size_t)bcol * K)
                                                        : (B1 + (size_t)(bcol - 6144) * K);
  f32x4 acc[8][4];
#pragma unroll
  for (int m = 0; m < 8; m++)
#pragma unroll
    for (int n = 0; n < 4; n++) acc[m][n] = (f32x4)0.f;

  auto stageU = [&](int TT, int s) {
    if (TT >= NT) return;
    unsigned short* lb = sm + (TT & 1) * 32768 + s * 8192;
    int kt = TT << 6;
    const unsigned short* gb = (s & 1) ? Bb : Ab;
    int ro = (s >> 1) << 7;
#pragma unroll
    for (int i = 0; i < 2; ++i) {
      int c = i * 512 + tid;
      int pos = c >> 3, pb = c & 7;
      gload16(gb + (size_t)(ro + pos) * K + kt + ((pb ^ (pos & 7)) << 3), lb + c * 8);
    }
  };

  // prologue: tile 0's 4 slots; wait for slots 0,1,3 (unit 2 may stay in flight)
  stageU(0, 0); stageU(0, 1); stageU(0, 3); stageU(0, 2);
  asm volatile("s_waitcnt vmcnt(2)" ::: "memory");
  __builtin_amdgcn_s_barrier();
  asm volatile("" ::: "memory");

  int bslot = (wn >> 1) ? 3 : 1;
  int bposb = (wn & 1) * 64;

  for (int T = 0; T < NT; ++T) {
    const unsigned short* bufb = sm + (T & 1) * 32768;
    const unsigned short* Bbase = bufb + bslot * 8192;
    short8 bfr[4][2], af[4][2];
    // ---- phase 0: C rows 0..127 ----
#pragma unroll
    for (int ni = 0; ni < 4; ++ni) {
      int pos = bposb + ni * 16 + l15;
#pragma unroll
      for (int ks = 0; ks < 2; ++ks)
        bfr[ni][ks] = *(const short8*)(Bbase + pos * 64 + (((ks * 4 + l4) ^ (pos & 7)) << 3));
    }
#pragma unroll
    for (int mi = 0; mi < 4; ++mi) {
      int pos = wm * 64 + mi * 16 + l15;
#pragma unroll
      for (int ks = 0; ks < 2; ++ks)
        af[mi][ks] = *(const short8*)(bufb + pos * 64 + (((ks * 4 + l4) ^ (pos & 7)) << 3));
    }
    stageU(T + 1, 0); stageU(T + 1, 1); stageU(T + 1, 3);
    __builtin_amdgcn_s_setprio(1);
#pragma unroll
    for (int mi = 0; mi < 4; ++mi)
#pragma unroll
      for (int ni = 0; ni < 4; ++ni)
#pragma unroll
        for (int ks = 0; ks < 2; ++ks) acc[mi][ni] = MFMA(af[mi][ks], bfr[ni][ks], acc[mi][ni]);
    __builtin_amdgcn_s_setprio(0);
    asm volatile("s_waitcnt vmcnt(6)" ::: "memory");
    __builtin_amdgcn_s_barrier();
    asm volatile("" ::: "memory");
    // ---- phase 1: C rows 128..255 ----
    const unsigned short* A1 = bufb + 2 * 8192;
#pragma unroll
    for (int mi = 0; mi < 4; ++mi) {
      int pos = wm * 64 + mi * 16 + l15;
#pragma unroll
      for (int ks = 0; ks < 2; ++ks)
        af[mi][ks] = *(const short8*)(A1 + pos * 64 + (((ks * 4 + l4) ^ (pos & 7)) << 3));
    }
    stageU(T + 1, 2);
    __builtin_amdgcn_s_setprio(1);
#pragma unroll
    for (int mi = 0; mi < 4; ++mi)
#pragma unroll
      for (int ni = 0; ni < 4; ++ni)
#pragma unroll
        for (int ks = 0; ks < 2; ++ks)
          acc[4 + mi][ni] = MFMA(af[mi][ks], bfr[ni][ks], acc[4 + mi][ni]);
    __builtin_amdgcn_s_setprio(0);
    asm volatile("s_waitcnt vmcnt(2)" ::: "memory");
    __builtin_amdgcn_s_barrier();
    asm volatile("" ::: "memory");
  }

#pragma unroll
  for (int mf = 0; mf < 8; ++mf)
#pragma unroll
    for (int r = 0; r < 4; ++r) {
      int row = brow + (mf >> 2) * 128 + wm * 64 + (mf & 3) * 16 + l4 * 4 + r;
#pragma unroll
      for (int ni = 0; ni < 4; ++ni) {
        int col = bcol + wn * 64 + ni * 16 + l15;
        float v = acc[mf][ni][r];
        if (MODE == 0) {
          if (col < 6144) {
            float sv = v / (1.f + __expf(-v));  // silu
            int h = col / 384, dd = col - h * 384;
            int b = row >> 12, t = row & 4095;
            size_t base = ((size_t)(b * 16 + h) * 4096 + t) * 128;
            if (dd < 128) o_q[base + dd] = f2b(sv);
            else if (dd < 256) o_k[base + dd - 128] = f2b(sv);
            else o_v[base + dd - 256] = f2b(sv);
          } else {
            float gv = 1.f / (1.f + __expf(-v));  // sigmoid
            o_g[(size_t)row * 2048 + (col - 6144)] = f2b(gv);
          }
        } else {
          o_f[(size_t)row * 2048 + col] = v;
        }
      }
    }
}

// ---------------- per-block KV contribution: kvT[e][d] = sum_t V[t][e] * K[t][d]*kd[t] ----------------
__global__ __launch_bounds__(256) void k_kvblk(const unsigned short* __restrict__ kk,
                                               const unsigned short* __restrict__ vv,
                                               const float* __restrict__ slope,
                                               unsigned short* __restrict__ kvT) {
  int gid = blockIdx.x;  // 512 = bh*16 + blk
  int bh = gid >> 4, blk = gid & 15;
  float s = slope[bh & 15];
  __shared__ unsigned short kT[128][72];
  __shared__ unsigned short vT[128][72];
  int tid = threadIdx.x, w = tid >> 6, lane = tid & 63;
  int wrow = (w >> 1) * 64, wcol = (w & 1) * 64;
  f32x4 acc[4][4];
#pragma unroll
  for (int m = 0; m < 4; m++)
#pragma unroll
    for (int n = 0; n < 4; n++) acc[m][n] = (f32x4)0.f;
  const unsigned short* kb = kk + ((size_t)bh * 4096 + blk * 256) * 128;
  const unsigned short* vb = vv + ((size_t)bh * 4096 + blk * 256) * 128;
  int tt = tid & 63, c0 = (tid >> 6) * 32;
  for (int tc = 0; tc < 4; ++tc) {
    __syncthreads();
    int tg = tc * 64 + tt;
    float kd = __expf(-s * (float)(255 - tg));
#pragma unroll
    for (int g = 0; g < 4; ++g) {
      int c = c0 + g * 8;
      short8 k8 = *(const short8*)(kb + (size_t)tg * 128 + c);
      short8 v8 = *(const short8*)(vb + (size_t)tg * 128 + c);
#pragma unroll
      for (int j = 0; j < 8; ++j) {
        kT[c + j][tt] = f2b(b2f((unsigned short)k8[j]) * kd);
        vT[c + j][tt] = (unsigned short)v8[j];
      }
    }
    __syncthreads();
#pragma unroll
    for (int kx = 0; kx < 64; kx += 32) {
      int ko = kx + (lane >> 4) * 8;
      short8 af[4], bfr[4];
#pragma unroll
      for (int m = 0; m < 4; m++) af[m] = *(const short8*)&vT[wrow + m * 16 + (lane & 15)][ko];
#pragma unroll
      for (int n = 0; n < 4; n++) bfr[n] = *(const short8*)&kT[wcol + n * 16 + (lane & 15)][ko];
#pragma unroll
      for (int m = 0; m < 4; m++)
#pragma unroll
        for (int n = 0; n < 4; n++) acc[m][n] = MFMA(af[m], bfr[n], acc[m][n]);
    }
  }
  unsigned short* op = kvT + (size_t)gid * 16384;
#pragma unroll
  for (int m = 0; m < 4; m++)
#pragma unroll
    for (int r = 0; r < 4; r++) {
      int e = wrow + m * 16 + (lane >> 4) * 4 + r;
#pragma unroll
      for (int n = 0; n < 4; n++) {
        int d = wcol + n * 16 + (lane & 15);
        op[e * 128 + d] = f2b(acc[m][n][r]);
      }
    }
}

// ---------------- decay prefix scan over blocks (in place: kvT[i] := state before block i) ----------------
__global__ void k_scan(unsigned short* kvT, const float* __restrict__ slope) {
  int gid = blockIdx.x;  // 2048
  int bh = gid >> 6;
  int eo = (gid & 63) * 256 + threadIdx.x;  // 0..16383
  float s = slope[bh & 15];
  float bd = __expf(-s * 256.f);
  float st = 0.f;
  size_t base = (size_t)bh * 16 * 16384 + eo;
#pragma unroll
  for (int i = 0; i < 16; ++i) {
    unsigned short c = kvT[base + (size_t)i * 16384];
    kvT[base + (size_t)i * 16384] = f2b(st);
    st = bd * st + b2f(c);
  }
}

// ---------------- per-block attention output ----------------
__global__ __launch_bounds__(256) void k_attn(const unsigned short* __restrict__ q,
                                              const unsigned short* __restrict__ kk,
                                              const unsigned short* __restrict__ vv,
                                              const unsigned short* __restrict__ kvT,
                                              const float* __restrict__ slope,
                                              unsigned short* __restrict__ attn) {
  int gid = blockIdx.x;  // 1024 = (bh*16 + blk)*2 + hf
  int hf = gid & 1, blk = (gid >> 1) & 15, bh = gid >> 5;
  float s = slope[bh & 15];
  __shared__ unsigned short k_sh[64][136];
  __shared__ unsigned short vT_sh[128][72];
  __shared__ unsigned short s_sh[4][32][72];
  int tid = threadIdx.x, w = tid >> 6, lane = tid & 63;
  int mm0 = hf * 128 + w * 32;  // wave's first within-block row
  const unsigned short* qb = q + ((size_t)bh * 4096 + blk * 256) * 128;
  const unsigned short* kvb = kvT + (size_t)(bh * 16 + blk) * 16384;
  f32x4 acc[2][8];
#pragma unroll
  for (int m = 0; m < 2; m++)
#pragma unroll
    for (int n = 0; n < 8; n++) acc[m][n] = (f32x4)0.f;
  // inter-block: (q) @ KV_pre   (row-scale by q_decay afterwards)
#pragma unroll
  for (int kx = 0; kx < 128; kx += 32) {
    int ko = kx + (lane >> 4) * 8;
    short8 af[2], bfr[8];
#pragma unroll
    for (int mi = 0; mi < 2; mi++)
      af[mi] = *(const short8*)(qb + (size_t)(mm0 + mi * 16 + (lane & 15)) * 128 + ko);
#pragma unroll
    for (int ni = 0; ni < 8; ni++)
      bfr[ni] = *(const short8*)(kvb + (size_t)(ni * 16 + (lane & 15)) * 128 + ko);
#pragma unroll
    for (int mi = 0; mi < 2; mi++)
#pragma unroll
      for (int ni = 0; ni < 8; ni++) acc[mi][ni] = MFMA(af[mi], bfr[ni], acc[mi][ni]);
  }
#pragma unroll
  for (int mi = 0; mi < 2; mi++)
#pragma unroll
    for (int r = 0; r < 4; r++) {
      float qd = __expf(-s * (float)(mm0 + mi * 16 + (lane >> 4) * 4 + r + 1));
#pragma unroll
      for (int ni = 0; ni < 8; ni++) acc[mi][ni][r] *= qd;
    }
  // intra-block: masked quadratic attention, 64-wide t-chunks
  int nchunk = 2 * (hf + 1);
  for (int tc = 0; tc < nchunk; ++tc) {
    __syncthreads();
    {  // stage K chunk rows [t][d]
      int t2 = tid >> 2, c = (tid & 3) * 32;
      const unsigned short* kp = kk + ((size_t)bh * 4096 + blk * 256 + tc * 64 + t2) * 128 + c;
#pragma unroll
      for (int g = 0; g < 4; ++g) *(short8*)&k_sh[t2][c + g * 8] = *(const short8*)(kp + g * 8);
    }
    {  // stage V^T chunk [e][t]
      int t2 = tid & 63, e0 = (tid >> 6) * 32;
      const unsigned short* vp = vv + ((size_t)bh * 4096 + blk * 256 + tc * 64 + t2) * 128 + e0;
#pragma unroll
      for (int g = 0; g < 4; ++g) {
        short8 v8 = *(const short8*)(vp + g * 8);
#pragma unroll
        for (int j = 0; j < 8; ++j) vT_sh[e0 + g * 8 + j][t2] = (unsigned short)v8[j];
      }
    }
    __syncthreads();
    if (tc * 64 <= mm0 + 31) {
      f32x4 sa[2][4];
#pragma unroll
      for (int m = 0; m < 2; m++)
#pragma unroll
        for (int n = 0; n < 4; n++) sa[m][n] = (f32x4)0.f;
#pragma unroll
      for (int kx = 0; kx < 128; kx += 32) {
        int ko = kx + (lane >> 4) * 8;
        short8 af[2], bfr[4];
#pragma unroll
        for (int mi = 0; mi < 2; mi++)
          af[mi] = *(const short8*)(qb + (size_t)(mm0 + mi * 16 + (lane & 15)) * 128 + ko);
#pragma unroll
        for (int ni = 0; ni < 4; ni++) bfr[ni] = *(const short8*)&k_sh[ni * 16 + (lane & 15)][ko];
#pragma unroll
        for (int mi = 0; mi < 2; mi++)
#pragma unroll
          for (int ni = 0; ni < 4; ni++) sa[mi][ni] = MFMA(af[mi], bfr[ni], sa[mi][ni]);
      }
      // mask * decay, to bf16, into per-wave S tile
#pragma unroll
      for (int mi = 0; mi < 2; mi++)
#pragma unroll
        for (int ni = 0; ni < 4; ni++)
#pragma unroll
          for (int r = 0; r < 4; r++) {
            int mm = mm0 + mi * 16 + (lane >> 4) * 4 + r;
            int ttg = tc * 64 + ni * 16 + (lane & 15);
            int diff = mm - ttg;
            float val = (diff >= 0) ? sa[mi][ni][r] * __expf(-s * (float)diff) : 0.f;
            s_sh[w][mi * 16 + (lane >> 4) * 4 + r][ni * 16 + (lane & 15)] = f2b(val);
          }
      // O += S @ V
#pragma unroll
      for (int k2 = 0; k2 < 64; k2 += 32) {
        int ko2 = k2 + (lane >> 4) * 8;
        short8 a2[2];
#pragma unroll
        for (int mi = 0; mi < 2; mi++)
          a2[mi] = *(const short8*)&s_sh[w][mi * 16 + (lane & 15)][ko2];
#pragma unroll
        for (int ni = 0; ni < 8; ni++) {
          short8 b2 = *(const short8*)&vT_sh[ni * 16 + (lane & 15)][ko2];
#pragma unroll
          for (int mi = 0; mi < 2; mi++) acc[mi][ni] = MFMA(a2[mi], b2, acc[mi][ni]);
        }
      }
    }
  }
  int b = bh >> 4, h = bh & 15;
#pragma unroll
  for (int mi = 0; mi < 2; mi++)
#pragma unroll
    for (int r = 0; r < 4; r++) {
      int mm = mm0 + mi * 16 + (lane >> 4) * 4 + r;
      size_t rowp = ((size_t)b * 4096 + blk * 256 + mm) * 2048 + h * 128;
#pragma unroll
      for (int ni = 0; ni < 8; ni++) attn[rowp + ni * 16 + (lane & 15)] = f2b(acc[mi][ni][r]);
    }
}

// ---------------- RMSNorm + gate ----------------
__global__ __launch_bounds__(256) void k_norm(const unsigned short* __restrict__ attn,
                                              const unsigned short* __restrict__ gate,
                                              const float* __restrict__ nw,
                                              unsigned short* __restrict__ y) {
  int row = blockIdx.x;  // 8192
  int tid = threadIdx.x, w = tid >> 6, lane = tid & 63;
  const unsigned short* ap = attn + (size_t)row * 2048 + tid * 8;
  const unsigned short* gp = gate + (size_t)row * 2048 + tid * 8;
  short8 a8 = *(const short8*)ap;
  float vals[8];
  float ss = 0.f;
#pragma unroll
  for (int j = 0; j < 8; ++j) {
    vals[j] = b2f((unsigned short)a8[j]);
    ss += vals[j] * vals[j];
  }
#pragma unroll
  for (int off = 32; off > 0; off >>= 1) ss += __shfl_down(ss, off, 64);
  __shared__ float red[4];
  if (lane == 0) red[w] = ss;
  __syncthreads();
  float tot = red[0] + red[1] + red[2] + red[3];
  float rms = rsqrtf(tot * (1.f / 2048.f) + 1.1920929e-07f);
  short8 g8 = *(const short8*)gp;
  short8 o;
#pragma unroll
  for (int j = 0; j < 8; ++j)
    o[j] = (short)f2b(vals[j] * rms * nw[tid * 8 + j] * b2f((unsigned short)g8[j]));
  *(short8*)(y + (size_t)row * 2048 + tid * 8) = o;
}

extern "C" void kernel_launch(void* const* d_in, const int* in_sizes, int n_in, void* d_out,
                              int out_size, void* d_ws, size_t ws_size, hipStream_t stream) {
  const float* x = (const float*)d_in[0];
  const float* slope = (const float*)d_in[1];
  const float* Wqkv = (const float*)d_in[2];
  const float* Wg = (const float*)d_in[3];
  const float* nw = (const float*)d_in[4];
  const float* Wo = (const float*)d_in[5];
  float* out = (float*)d_out;

  unsigned short* q = (unsigned short*)d_ws;               // 16,777,216 elems
  unsigned short* k = q + 16777216;                        // 16,777,216
  unsigned short* v = k + 16777216;                        // 16,777,216
  unsigned short* gate = v + 16777216;                     // 16,777,216
  unsigned short* xb = gate + 16777216;                    // 16,777,216
  unsigned short* wqkvb = xb + 16777216;                   // 12,582,912
  unsigned short* wgb = wqkvb + 12582912;                  // 4,194,304
  unsigned short* wob = wgb + 4194304;                     // 4,194,304
  unsigned short* kvT = wob + 4194304;                     // 8,388,608
  unsigned short* attn = wqkvb;  // alias: wqkvb+wgb dead after GEMM1 (exactly 16,777,216)
  unsigned short* y = xb;        // alias: xb dead after GEMM1

  k_f2b<<<2048, 256, 0, stream>>>(x, xb, 16777216L);
  k_f2b<<<2048, 256, 0, stream>>>(Wqkv, wqkvb, 12582912L);
  k_f2b<<<1024, 256, 0, stream>>>(Wg, wgb, 4194304L);
  k_f2b<<<1024, 256, 0, stream>>>(Wo, wob, 4194304L);

  k_gemm<0><<<1024, 512, 0, stream>>>(xb, wqkvb, wgb, q, k, v, gate, nullptr);
  k_kvblk<<<512, 256, 0, stream>>>(k, v, slope, kvT);
  k_scan<<<2048, 256, 0, stream>>>(kvT, slope);
  k_attn<<<1024, 256, 0, stream>>>(q, k, v, kvT, slope, attn);
  k_norm<<<8192, 256, 0, stream>>>(attn, gate, nw, y);
  k_gemm<1><<<256, 512, 0, stream>>>(y, wob, nullptr, nullptr, nullptr, nullptr, nullptr, out);
}